// Round 1
// baseline (1575.657 us; speedup 1.0000x reference)
//
#include <hip/hip_runtime.h>
#include <math.h>

// Problem dims
#define BB 16
#define T0 400
#define F0 40
#define HH 512
#define T1 396   // after conv1 (k5,d1)
#define T2 392   // after conv2 (k3,d2)
#define T3 384   // after conv3 (k3,d4)
#define KBOT 262144

// ws layout (float offsets). Total 13,804,544 floats = 55.2 MB.
#define OFF_A 0          // 16*512*396 = 3244032  (y1, later x4=x)
#define OFF_B 3244032    // 16*512*392 = 3211264  (y2, later x5=xb)
#define OFF_C 6455296    // 16*512*384 = 3145728  (y3; later aliased by partials P)
#define OFF_M 9601024    // 16*512*512 = 4194304  (outer-product m)
#define OFF_H 13795328   // 16*512 = 8192         (bottleneck h)
#define OFF_SC 13803520  // 512 bn scale
#define OFF_SH 13804032  // 512 bn shift

// ---------------- conv1: [16,400,40] -> [16,512,396], weights [512][40][5] ----------------
__global__ __launch_bounds__(256) void conv1_kernel(
    const float* __restrict__ in, const float* __restrict__ w, float* __restrict__ out) {
  __shared__ float wsm[200];
  int bh = blockIdx.x;              // b*512 + h
  int b = bh >> 9, h = bh & 511;
  for (int i = threadIdx.x; i < 200; i += 256) wsm[i] = w[h * 200 + i];
  __syncthreads();
  const float* xin = in + b * (T0 * F0);
  float* o = out + bh * T1;
  for (int t = threadIdx.x; t < T1; t += 256) {
    float s = 0.f;
    #pragma unroll
    for (int k = 0; k < 5; ++k) {
      const float* xr = xin + (t + k) * F0;
      #pragma unroll
      for (int f4 = 0; f4 < 10; ++f4) {
        float4 xv = *(const float4*)(xr + f4 * 4);
        s = fmaf(xv.x, wsm[(f4 * 4 + 0) * 5 + k], s);
        s = fmaf(xv.y, wsm[(f4 * 4 + 1) * 5 + k], s);
        s = fmaf(xv.z, wsm[(f4 * 4 + 2) * 5 + k], s);
        s = fmaf(xv.w, wsm[(f4 * 4 + 3) * 5 + k], s);
      }
    }
    o[t] = s;  // bias omitted: BN (batch-stats) cancels per-channel constants exactly
  }
}

// ---------------- BN (training-mode batch stats over (B,T)) -> scale/shift ----------------
__global__ __launch_bounds__(256) void bn_stats_kernel(
    const float* __restrict__ x, int T, const float* __restrict__ g,
    const float* __restrict__ beta, float* __restrict__ sc, float* __restrict__ sh) {
  int c = blockIdx.x;
  float s = 0.f, s2 = 0.f;
  for (int b = 0; b < BB; ++b) {
    const float* row = x + (b * HH + c) * T;
    for (int t = threadIdx.x; t < T; t += 256) {
      float v = row[t];
      s += v; s2 = fmaf(v, v, s2);
    }
  }
  #pragma unroll
  for (int off = 32; off > 0; off >>= 1) {
    s += __shfl_down(s, off);
    s2 += __shfl_down(s2, off);
  }
  __shared__ float rs[4], rs2[4];
  int tid = threadIdx.x;
  if ((tid & 63) == 0) { rs[tid >> 6] = s; rs2[tid >> 6] = s2; }
  __syncthreads();
  if (tid == 0) {
    float S = rs[0] + rs[1] + rs[2] + rs[3];
    float S2 = rs2[0] + rs2[1] + rs2[2] + rs2[3];
    float n = (float)(BB * T);
    float mean = S / n;
    float var = S2 / n - mean * mean;   // biased var, matches jnp.var
    float scale = g[c] * rsqrtf(var + 1e-5f);
    sc[c] = scale;
    sh[c] = beta[c] - mean * scale;
  }
}

__global__ __launch_bounds__(256) void bn_apply_kernel(
    float* __restrict__ x, int T, const float* __restrict__ sc, const float* __restrict__ sh) {
  int bh = blockIdx.x;
  int c = bh & 511;
  float scale = sc[c], shift = sh[c];
  float* row = x + bh * T;
  for (int t = threadIdx.x; t < T; t += 256) {
    float v = fmaf(row[t], scale, shift);
    row[t] = fminf(fmaxf(v, 0.f), 20.f);   // relu20
  }
}

// -------- generic conv/pointwise as GEMM: C[512][B*TOUT] = W[512][K] * im2col(X) --------
// KTAPS=3 (dilated conv) or 1 (pointwise). 64x64 tile, 256 thr, 4x4 micro-tile, BK=16.
template <int KTAPS, int DIL, int TIN, int TOUT, int K>
__global__ __launch_bounds__(256) void gemm_conv(
    const float* __restrict__ A, const float* __restrict__ X, float* __restrict__ Y) {
  __shared__ float As[16][64];
  __shared__ float Bs[16][64];
  int m0 = blockIdx.y * 64;
  int n0 = blockIdx.x * 64;
  int tid = threadIdx.x;
  int tx = tid & 15, ty = tid >> 4;
  int ar = tid >> 2, ac = (tid & 3) * 4;
  int bi = tid >> 4, bj = (tid & 15) * 4;
  float acc[4][4] = {};
  for (int k0 = 0; k0 < K; k0 += 16) {
    float4 av = *(const float4*)(A + (m0 + ar) * K + k0 + ac);
    As[ac + 0][ar] = av.x; As[ac + 1][ar] = av.y;
    As[ac + 2][ar] = av.z; As[ac + 3][ar] = av.w;
    int kk = k0 + bi;
    int c, kt;
    if (KTAPS == 3) { c = kk / 3; kt = kk - c * 3; } else { c = kk; kt = 0; }
    const float* xrow = X + c * TIN + DIL * kt;
    #pragma unroll
    for (int q = 0; q < 4; ++q) {
      int n = n0 + bj + q;
      int b = n / TOUT, t = n - b * TOUT;
      Bs[bi][bj + q] = xrow[b * (HH * TIN) + t];
    }
    __syncthreads();
    #pragma unroll
    for (int kk2 = 0; kk2 < 16; ++kk2) {
      float4 a4 = *(const float4*)&As[kk2][ty * 4];
      float4 b4 = *(const float4*)&Bs[kk2][tx * 4];
      float avv[4] = {a4.x, a4.y, a4.z, a4.w};
      float bvv[4] = {b4.x, b4.y, b4.z, b4.w};
      #pragma unroll
      for (int i = 0; i < 4; ++i)
        #pragma unroll
        for (int j = 0; j < 4; ++j) acc[i][j] = fmaf(avv[i], bvv[j], acc[i][j]);
    }
    __syncthreads();
  }
  #pragma unroll
  for (int i = 0; i < 4; ++i) {
    int m = m0 + ty * 4 + i;
    #pragma unroll
    for (int j = 0; j < 4; ++j) {
      int n = n0 + tx * 4 + j;
      int b = n / TOUT, t = n - b * TOUT;
      Y[(b * HH + m) * TOUT + t] = acc[i][j];
    }
  }
}

// -------- outer product: m[b][i][j] = sum_t x[b,i,t]*xb[b,j,t]  (per-b 512x512x384 GEMM) --------
__global__ __launch_bounds__(256) void outer_kernel(
    const float* __restrict__ x, const float* __restrict__ xb, float* __restrict__ mo) {
  int b = blockIdx.z;
  const float* Ab = x + b * HH * T3;
  const float* Bb = xb + b * HH * T3;
  float* Cb = mo + b * HH * HH;
  __shared__ float As[16][64], Bs[16][64];
  int tid = threadIdx.x;
  int tx = tid & 15, ty = tid >> 4;
  int m0 = blockIdx.y * 64, n0 = blockIdx.x * 64;
  int ar = tid >> 2, ac = (tid & 3) * 4;
  float acc[4][4] = {};
  for (int k0 = 0; k0 < T3; k0 += 16) {
    float4 av = *(const float4*)(Ab + (m0 + ar) * T3 + k0 + ac);
    float4 bv = *(const float4*)(Bb + (n0 + ar) * T3 + k0 + ac);
    As[ac + 0][ar] = av.x; As[ac + 1][ar] = av.y; As[ac + 2][ar] = av.z; As[ac + 3][ar] = av.w;
    Bs[ac + 0][ar] = bv.x; Bs[ac + 1][ar] = bv.y; Bs[ac + 2][ar] = bv.z; Bs[ac + 3][ar] = bv.w;
    __syncthreads();
    #pragma unroll
    for (int kk = 0; kk < 16; ++kk) {
      float4 a4 = *(const float4*)&As[kk][ty * 4];
      float4 b4 = *(const float4*)&Bs[kk][tx * 4];
      float avv[4] = {a4.x, a4.y, a4.z, a4.w};
      float bvv[4] = {b4.x, b4.y, b4.z, b4.w};
      #pragma unroll
      for (int i = 0; i < 4; ++i)
        #pragma unroll
        for (int j = 0; j < 4; ++j) acc[i][j] = fmaf(avv[i], bvv[j], acc[i][j]);
    }
    __syncthreads();
  }
  #pragma unroll
  for (int i = 0; i < 4; ++i) {
    float4 v = make_float4(acc[i][0], acc[i][1], acc[i][2], acc[i][3]);
    *(float4*)(Cb + (m0 + ty * 4 + i) * HH + n0 + tx * 4) = v;
  }
}

// -------- bottleneck split-K: h[b][n] = sum_k m[b][k]*W[n][k]; W is 537MB -> HBM-bound --------
// grid (256 k-chunks of 1024, 4 n-tiles of 128). Deterministic partials P[256][16][512].
__global__ __launch_bounds__(256) void bot_partial_kernel(
    const float* __restrict__ m, const float* __restrict__ W, float* __restrict__ P) {
  __shared__ float Ws[32][128];
  __shared__ float Ms[32][16];
  int ic = blockIdx.x;
  int n0 = blockIdx.y * 128;
  int tid = threadIdx.x;
  int kb = ic * 1024;
  int wr = tid >> 1;            // 0..127 (n row for W staging)
  int wc = (tid & 1) * 16;      // k sub-offset
  int nl = (tid & 63) * 2;      // n pair for compute
  int bq = (tid >> 6) * 4;      // b quad for compute (wave-uniform -> LDS broadcast)
  float acc[4][2] = {};
  for (int k0 = kb; k0 < kb + 1024; k0 += 32) {
    #pragma unroll
    for (int q = 0; q < 4; ++q) {
      float4 wv = *(const float4*)(W + (n0 + wr) * KBOT + k0 + wc + q * 4);
      Ws[wc + q * 4 + 0][wr] = wv.x; Ws[wc + q * 4 + 1][wr] = wv.y;
      Ws[wc + q * 4 + 2][wr] = wv.z; Ws[wc + q * 4 + 3][wr] = wv.w;
    }
    if (tid < 128) {
      int b = tid >> 3, kg = (tid & 7) * 4;
      float4 mv = *(const float4*)(m + b * KBOT + k0 + kg);
      Ms[kg + 0][b] = mv.x; Ms[kg + 1][b] = mv.y; Ms[kg + 2][b] = mv.z; Ms[kg + 3][b] = mv.w;
    }
    __syncthreads();
    #pragma unroll
    for (int kk = 0; kk < 32; ++kk) {
      float2 w2 = *(const float2*)&Ws[kk][nl];
      float4 m4 = *(const float4*)&Ms[kk][bq];
      acc[0][0] = fmaf(m4.x, w2.x, acc[0][0]); acc[0][1] = fmaf(m4.x, w2.y, acc[0][1]);
      acc[1][0] = fmaf(m4.y, w2.x, acc[1][0]); acc[1][1] = fmaf(m4.y, w2.y, acc[1][1]);
      acc[2][0] = fmaf(m4.z, w2.x, acc[2][0]); acc[2][1] = fmaf(m4.z, w2.y, acc[2][1]);
      acc[3][0] = fmaf(m4.w, w2.x, acc[3][0]); acc[3][1] = fmaf(m4.w, w2.y, acc[3][1]);
    }
    __syncthreads();
  }
  #pragma unroll
  for (int i = 0; i < 4; ++i) {
    float* row = P + (ic * 16 + bq + i) * 512 + n0;
    *(float2*)&row[nl] = make_float2(acc[i][0], acc[i][1]);
  }
}

__global__ __launch_bounds__(256) void bot_reduce_kernel(
    const float* __restrict__ P, float* __restrict__ h) {
  int idx = blockIdx.x * 256 + threadIdx.x;  // b*512+n
  float s[8] = {};
  for (int ic = 0; ic < 256; ic += 8) {
    #pragma unroll
    for (int q = 0; q < 8; ++q) s[q] += P[(ic + q) * 8192 + idx];
  }
  h[idx] = ((s[0] + s[1]) + (s[2] + s[3])) + ((s[4] + s[5]) + (s[6] + s[7]));
  // bot_b omitted: bn2d subtracts per-feature batch mean -> constants cancel
}

// -------- bn2d + relu20 + emb GEMV + L2-normalize*10 --------
__global__ __launch_bounds__(512) void final_kernel(
    const float* __restrict__ h, const float* __restrict__ gb, const float* __restrict__ bb,
    const float* __restrict__ embw, const float* __restrict__ embb, float* __restrict__ out) {
  __shared__ float hn[512];
  __shared__ float red[8];
  int b = blockIdx.x, e = threadIdx.x;
  float s = 0.f, s2 = 0.f;
  #pragma unroll
  for (int q = 0; q < BB; ++q) {
    float v = h[q * 512 + e];
    s += v; s2 = fmaf(v, v, s2);
  }
  float mean = s * (1.f / BB);
  float var = s2 * (1.f / BB) - mean * mean;
  float scale = gb[e] * rsqrtf(var + 1e-5f);
  float val = fmaf(h[b * 512 + e] - mean, scale, bb[e]);
  hn[e] = fminf(fmaxf(val, 0.f), 20.f);
  __syncthreads();
  float acc = 0.f;
  const float* wr = embw + e * 512;
  for (int c = 0; c < 512; c += 4) {
    float4 w4 = *(const float4*)(wr + c);
    float4 h4 = *(const float4*)&hn[c];
    acc = fmaf(w4.x, h4.x, acc); acc = fmaf(w4.y, h4.y, acc);
    acc = fmaf(w4.z, h4.z, acc); acc = fmaf(w4.w, h4.w, acc);
  }
  acc += embb[e];
  float sq = acc * acc;
  #pragma unroll
  for (int off = 32; off > 0; off >>= 1) sq += __shfl_down(sq, off);
  if ((e & 63) == 0) red[e >> 6] = sq;
  __syncthreads();
  float tot = 0.f;
  #pragma unroll
  for (int q = 0; q < 8; ++q) tot += red[q];
  float norm = sqrtf(tot + 1e-10f);
  out[b * 512 + e] = acc * (10.f / norm);
}

extern "C" void kernel_launch(void* const* d_in, const int* in_sizes, int n_in,
                              void* d_out, int out_size, void* d_ws, size_t ws_size,
                              hipStream_t stream) {
  const float* input_x = (const float*)d_in[0];
  const float* w1 = (const float*)d_in[1];
  const float* g1 = (const float*)d_in[3];  const float* b1 = (const float*)d_in[4];
  const float* w2 = (const float*)d_in[5];
  const float* g2 = (const float*)d_in[7];  const float* b2 = (const float*)d_in[8];
  const float* w3 = (const float*)d_in[9];
  const float* g3 = (const float*)d_in[11]; const float* b3 = (const float*)d_in[12];
  const float* w4 = (const float*)d_in[13];
  const float* g4 = (const float*)d_in[15]; const float* b4 = (const float*)d_in[16];
  const float* w5 = (const float*)d_in[17];
  const float* g5 = (const float*)d_in[19]; const float* b5 = (const float*)d_in[20];
  const float* botw = (const float*)d_in[21];
  const float* gb = (const float*)d_in[23]; const float* bb = (const float*)d_in[24];
  const float* embw = (const float*)d_in[25]; const float* embb = (const float*)d_in[26];

  float* ws = (float*)d_ws;
  float* A  = ws + OFF_A;
  float* Bf = ws + OFF_B;
  float* C  = ws + OFF_C;
  float* M  = ws + OFF_M;
  float* P  = C;               // alias: C dead after lin4 consumes it
  float* h  = ws + OFF_H;
  float* sc = ws + OFF_SC;
  float* sh = ws + OFF_SH;
  float* out = (float*)d_out;

  conv1_kernel<<<BB * HH, 256, 0, stream>>>(input_x, w1, A);
  bn_stats_kernel<<<HH, 256, 0, stream>>>(A, T1, g1, b1, sc, sh);
  bn_apply_kernel<<<BB * HH, 256, 0, stream>>>(A, T1, sc, sh);

  gemm_conv<3, 2, T1, T2, 1536><<<dim3(BB * T2 / 64, 8), 256, 0, stream>>>(w2, A, Bf);
  bn_stats_kernel<<<HH, 256, 0, stream>>>(Bf, T2, g2, b2, sc, sh);
  bn_apply_kernel<<<BB * HH, 256, 0, stream>>>(Bf, T2, sc, sh);

  gemm_conv<3, 4, T2, T3, 1536><<<dim3(BB * T3 / 64, 8), 256, 0, stream>>>(w3, Bf, C);
  bn_stats_kernel<<<HH, 256, 0, stream>>>(C, T3, g3, b3, sc, sh);
  bn_apply_kernel<<<BB * HH, 256, 0, stream>>>(C, T3, sc, sh);

  gemm_conv<1, 0, T3, T3, 512><<<dim3(BB * T3 / 64, 8), 256, 0, stream>>>(w4, C, A);
  bn_stats_kernel<<<HH, 256, 0, stream>>>(A, T3, g4, b4, sc, sh);
  bn_apply_kernel<<<BB * HH, 256, 0, stream>>>(A, T3, sc, sh);

  gemm_conv<1, 0, T3, T3, 512><<<dim3(BB * T3 / 64, 8), 256, 0, stream>>>(w5, A, Bf);
  bn_stats_kernel<<<HH, 256, 0, stream>>>(Bf, T3, g5, b5, sc, sh);
  bn_apply_kernel<<<BB * HH, 256, 0, stream>>>(Bf, T3, sc, sh);

  outer_kernel<<<dim3(8, 8, 16), 256, 0, stream>>>(A, Bf, M);
  bot_partial_kernel<<<dim3(256, 4), 256, 0, stream>>>(M, botw, P);
  bot_reduce_kernel<<<32, 256, 0, stream>>>(P, h);
  final_kernel<<<16, 512, 0, stream>>>(h, gb, bb, embw, embb, out);
}

// Round 2
// 1097.037 us; speedup vs baseline: 1.4363x; 1.4363x over previous
//
#include <hip/hip_runtime.h>
#include <math.h>

#define BB 16
#define T0 400
#define HH 512
#define T1 396
#define T2 392
#define T3 384
#define KBOT 262144

typedef __attribute__((ext_vector_type(8))) short bf16x8;
typedef __attribute__((ext_vector_type(4))) float f32x4;

__device__ __forceinline__ short f2bf(float f) {
  unsigned u = __builtin_bit_cast(unsigned, f);
  u += 0x7fff + ((u >> 16) & 1);
  return (short)(u >> 16);
}

// ---------------- ws layout (float units) ----------------
#define OFF_Y1  0u          // 3,244,032
#define OFF_Y2  3244032u
#define OFF_Y3  6455296u
#define OFF_Y4  9601024u
#define OFF_Y5  12746752u
#define OFF_M   15892480u   // 4,194,304
#define OFF_P   20086784u   // 2,097,152
#define OFF_PP  22183936u   // 65,536
#define OFF_H   22249472u   // 8,192
#define OFF_SC  22257664u   // 5*1024 (sc_l at +l*1024, sh_l at +l*1024+512)
#define OFF_WPK 22262784u   // 2,260,992 bf16
#define OFF_XB0 23393280u   // 409,600 bf16
#define OFF_XB1 23598080u   // 3,244,032 bf16
#define OFF_XB2 25220096u
#define OFF_XB3 26825728u
#define OFF_XB4 28398592u
#define OFF_X4F 29971456u   // 3,145,728 bf16 (frag layout)
#define OFF_X5F 31544320u

// packed-weight sub-offsets (bf16 units)
#define WP1 0
#define WP2 163840
#define WP3 950272
#define WP4 1736704
#define WP5 1998848

// -------- pack weights into MFMA A-fragment layout (bf16) --------
// flat frag index f: j=f&7, lane=(f>>3)&63, kb=(f>>9)%KB, mt=(f>>9)/KB
// m = mt*16 + (lane&15); k = kb*32 + (lane>>4)*8 + j
__global__ __launch_bounds__(256) void pack_weights(
    const float* __restrict__ w1, const float* __restrict__ w2,
    const float* __restrict__ w3, const float* __restrict__ w4,
    const float* __restrict__ w5, short* __restrict__ dst) {
  const int nelem[5] = {163840, 786432, 786432, 262144, 262144};
  const int kbv[5]   = {10, 48, 48, 16, 16};
  const int offv[5]  = {WP1, WP2, WP3, WP4, WP5};
  int widx = blockIdx.y;
  int f = blockIdx.x * 256 + threadIdx.x;
  if (f >= nelem[widx]) return;
  int j = f & 7, lane = (f >> 3) & 63, rest = f >> 9;
  int KB = kbv[widx];
  int kb = rest % KB, mt = rest / KB;
  int m = mt * 16 + (lane & 15);
  int k = kb * 32 + (lane >> 4) * 8 + j;
  float v;
  if (widx == 0) {
    int kt = k >> 6, fi = k & 63;              // K = kt*64 + f, f padded 40->64
    v = (fi < 40) ? w1[m * 200 + fi * 5 + kt] : 0.f;
  } else if (widx <= 2) {
    const float* w = (widx == 1) ? w2 : w3;
    int kt = k >> 9, c = k & 511;              // K = kt*512 + c
    v = w[m * 1536 + c * 3 + kt];
  } else {
    const float* w = (widx == 3) ? w4 : w5;
    v = w[m * 512 + k];
  }
  dst[offv[widx] + f] = f2bf(v);
}

// -------- input fp32 [16][400][40] -> bf16 [16][400][64] zero-padded --------
__global__ __launch_bounds__(256) void convert_in(
    const float* __restrict__ in, short* __restrict__ xb0) {
  int row = blockIdx.x * 4 + (threadIdx.x >> 6);
  int c = threadIdx.x & 63;
  float v = (c < 40) ? in[row * 40 + c] : 0.f;
  xb0[row * 64 + c] = f2bf(v);
}

// -------- MFMA GEMM: Y[n][m] = sum_k Wpk[m][k] * Xb_im2col[n][k] --------
// 64x64 block tile, 4 waves 2x2, each wave 2x2 MFMA 16x16x32 tiles.
// A frags direct from global (pre-packed); B staged in LDS frag layout.
template <int KTAPS, int DIL, int TIN, int TOUT, int CIN>
__global__ __launch_bounds__(256) void gemm_mfma(
    const short* __restrict__ Wpk, const short* __restrict__ Xb, float* __restrict__ Y) {
  constexpr int KBTOT = KTAPS * CIN / 32;
  __shared__ short Bfrag[4096];  // [ks2][nt4][lane64][8]
  int tid = threadIdx.x;
  int sn = tid >> 2;              // staging row 0..63
  int cb0 = (tid & 3) * 16;       // c-segment
  int cb1 = cb0 + 8;
  int n_glob = blockIdx.x * 64 + sn;
  int b = n_glob / TOUT, t = n_glob - b * TOUT;
  const short* xrow = Xb + (b * TIN + t) * CIN;
  int wave = tid >> 6, lane = tid & 63;
  int wm = wave >> 1, wn = wave & 1;
  int mt0 = blockIdx.y * 4 + wm * 2;
  const short* a_base0 = Wpk + mt0 * KBTOT * 512 + lane * 8;
  const short* a_base1 = a_base0 + KBTOT * 512;
  int wo0 = (((cb0 >> 5) * 4 + (sn >> 4)) * 64 + (sn & 15) + 16 * ((cb0 & 31) >> 3)) * 8;
  int wo1 = (((cb1 >> 5) * 4 + (sn >> 4)) * 64 + (sn & 15) + 16 * ((cb1 & 31) >> 3)) * 8;
  int ro = wn * 1024 + lane * 8;  // nt=wn*2 base; +512 for nt+1; +2048 for ks=1
  f32x4 acc00 = {0,0,0,0}, acc01 = {0,0,0,0}, acc10 = {0,0,0,0}, acc11 = {0,0,0,0};
  for (int kt = 0; kt < KTAPS; ++kt) {
    const short* xk = xrow + DIL * kt * CIN;
    for (int c0 = 0; c0 < CIN; c0 += 64) {
      bf16x8 v0 = *(const bf16x8*)(xk + c0 + cb0);
      bf16x8 v1 = *(const bf16x8*)(xk + c0 + cb1);
      *(bf16x8*)&Bfrag[wo0] = v0;
      *(bf16x8*)&Bfrag[wo1] = v1;
      __syncthreads();
      int kbase = (kt * CIN + c0) >> 5;
      #pragma unroll
      for (int ks = 0; ks < 2; ++ks) {
        bf16x8 a0 = *(const bf16x8*)(a_base0 + (kbase + ks) * 512);
        bf16x8 a1 = *(const bf16x8*)(a_base1 + (kbase + ks) * 512);
        bf16x8 b0 = *(const bf16x8*)&Bfrag[ro + ks * 2048];
        bf16x8 b1 = *(const bf16x8*)&Bfrag[ro + ks * 2048 + 512];
        acc00 = __builtin_amdgcn_mfma_f32_16x16x32_bf16(a0, b0, acc00, 0, 0, 0);
        acc01 = __builtin_amdgcn_mfma_f32_16x16x32_bf16(a0, b1, acc01, 0, 0, 0);
        acc10 = __builtin_amdgcn_mfma_f32_16x16x32_bf16(a1, b0, acc10, 0, 0, 0);
        acc11 = __builtin_amdgcn_mfma_f32_16x16x32_bf16(a1, b1, acc11, 0, 0, 0);
      }
      __syncthreads();
    }
  }
  int quad = lane >> 4, nl = lane & 15;
  int mb = blockIdx.y * 64 + wm * 32 + quad * 4;
  int nb = blockIdx.x * 64 + wn * 32;
  *(f32x4*)(Y + (nb + nl) * 512 + mb)           = acc00;
  *(f32x4*)(Y + (nb + 16 + nl) * 512 + mb)      = acc01;
  *(f32x4*)(Y + (nb + nl) * 512 + mb + 16)      = acc10;
  *(f32x4*)(Y + (nb + 16 + nl) * 512 + mb + 16) = acc11;
}

// -------- BN stats two-pass --------
__global__ __launch_bounds__(256) void bn_partial(
    const float* __restrict__ Y, int nrows, float* __restrict__ Pp) {
  int tid = threadIdx.x;
  float s0 = 0, s20 = 0, s1 = 0, s21 = 0;
  for (int r = blockIdx.x; r < nrows; r += 64) {
    float v0 = Y[r * 512 + tid];
    float v1 = Y[r * 512 + tid + 256];
    s0 += v0; s20 = fmaf(v0, v0, s20);
    s1 += v1; s21 = fmaf(v1, v1, s21);
  }
  float* base = Pp + blockIdx.x * 1024;
  base[tid] = s0; base[tid + 256] = s1;
  base[512 + tid] = s20; base[512 + tid + 256] = s21;
}

__global__ __launch_bounds__(512) void bn_final(
    const float* __restrict__ Pp, const float* __restrict__ g,
    const float* __restrict__ beta, float n, float* __restrict__ sc, float* __restrict__ sh) {
  int c = threadIdx.x;
  float S = 0, S2 = 0;
  for (int blk = 0; blk < 64; ++blk) {
    S += Pp[blk * 1024 + c];
    S2 += Pp[blk * 1024 + 512 + c];
  }
  float mean = S / n, var = S2 / n - mean * mean;
  float scale = g[c] * rsqrtf(var + 1e-5f);
  sc[c] = scale;
  sh[c] = beta[c] - mean * scale;
}

// -------- BN affine + relu20 + fp32->bf16, [n][512] layout --------
__global__ __launch_bounds__(256) void bn_apply_bf(
    const float* __restrict__ Y, const float* __restrict__ sc,
    const float* __restrict__ sh, short* __restrict__ Xb) {
  int idx = (blockIdx.x * 256 + threadIdx.x) * 8;
  int c = idx & 511;
  float4 a = *(const float4*)(Y + idx);
  float4 d = *(const float4*)(Y + idx + 4);
  float4 s0 = *(const float4*)(sc + c);
  float4 s1 = *(const float4*)(sc + c + 4);
  float4 h0 = *(const float4*)(sh + c);
  float4 h1 = *(const float4*)(sh + c + 4);
  bf16x8 o;
  o[0] = f2bf(fminf(fmaxf(fmaf(a.x, s0.x, h0.x), 0.f), 20.f));
  o[1] = f2bf(fminf(fmaxf(fmaf(a.y, s0.y, h0.y), 0.f), 20.f));
  o[2] = f2bf(fminf(fmaxf(fmaf(a.z, s0.z, h0.z), 0.f), 20.f));
  o[3] = f2bf(fminf(fmaxf(fmaf(a.w, s0.w, h0.w), 0.f), 20.f));
  o[4] = f2bf(fminf(fmaxf(fmaf(d.x, s1.x, h1.x), 0.f), 20.f));
  o[5] = f2bf(fminf(fmaxf(fmaf(d.y, s1.y, h1.y), 0.f), 20.f));
  o[6] = f2bf(fminf(fmaxf(fmaf(d.z, s1.z, h1.z), 0.f), 20.f));
  o[7] = f2bf(fminf(fmaxf(fmaf(d.w, s1.w, h1.w), 0.f), 20.f));
  *(bf16x8*)(Xb + idx) = o;
}

// -------- BN-apply + transpose [n=(b,t)][c] -> A-frag layout over (m=c, k=t) --------
// grid (tk=6, it=8, b=16)
__global__ __launch_bounds__(256) void apply_frag(
    const float* __restrict__ Y, const float* __restrict__ sc,
    const float* __restrict__ sh, short* __restrict__ Xf) {
  __shared__ float ysm[64][65];
  int tk = blockIdx.x, it = blockIdx.y, b = blockIdx.z;
  int tid = threadIdx.x;
  int ii = (tid & 15) * 4;
  #pragma unroll
  for (int p = 0; p < 4; ++p) {
    int tt = p * 16 + (tid >> 4);
    *(float4*)&ysm[tt][ii] =
        *(const float4*)(Y + ((b * 384) + tk * 64 + tt) * 512 + it * 64 + ii);
  }
  __syncthreads();
  int i_loc = tid & 63;
  int i = it * 64 + i_loc;
  float scale = sc[i], shift = sh[i];
  int mt = it * 4 + (i_loc >> 4);
  #pragma unroll
  for (int p = 0; p < 2; ++p) {
    int tq = p * 4 + (tid >> 6);
    bf16x8 pk;
    #pragma unroll
    for (int j = 0; j < 8; ++j) {
      float v = fmaf(ysm[tq * 8 + j][i_loc], scale, shift);
      pk[j] = f2bf(fminf(fmaxf(v, 0.f), 20.f));
    }
    int kb = tk * 2 + (tq >> 2);
    int lanew = (i_loc & 15) + 16 * (tq & 3);
    *(bf16x8*)(Xf + (((b * 32 + mt) * 12 + kb) * 64 + lanew) * 8) = pk;
  }
}

// -------- outer product via MFMA, LDS-free (both operands pre-packed frags) --------
// grid (jn=8, im=8, b=16); M[b][i][j] += sum_t x4[i,t]*x5[j,t]
__global__ __launch_bounds__(256) void outer_mfma(
    const short* __restrict__ Af, const short* __restrict__ Bf, float* __restrict__ M) {
  int b = blockIdx.z;
  int tid = threadIdx.x, wave = tid >> 6, lane = tid & 63;
  int wm = wave >> 1, wn = wave & 1;
  int mt0 = blockIdx.y * 4 + wm * 2;
  int nt0 = blockIdx.x * 4 + wn * 2;
  const short* pa0 = Af + (b * 32 + mt0) * 12 * 512 + lane * 8;
  const short* pa1 = pa0 + 12 * 512;
  const short* pb0 = Bf + (b * 32 + nt0) * 12 * 512 + lane * 8;
  const short* pb1 = pb0 + 12 * 512;
  f32x4 acc00 = {0,0,0,0}, acc01 = {0,0,0,0}, acc10 = {0,0,0,0}, acc11 = {0,0,0,0};
  #pragma unroll 4
  for (int kb = 0; kb < 12; ++kb) {
    bf16x8 a0 = *(const bf16x8*)(pa0 + kb * 512);
    bf16x8 a1 = *(const bf16x8*)(pa1 + kb * 512);
    bf16x8 b0 = *(const bf16x8*)(pb0 + kb * 512);
    bf16x8 b1 = *(const bf16x8*)(pb1 + kb * 512);
    acc00 = __builtin_amdgcn_mfma_f32_16x16x32_bf16(a0, b0, acc00, 0, 0, 0);
    acc01 = __builtin_amdgcn_mfma_f32_16x16x32_bf16(a0, b1, acc01, 0, 0, 0);
    acc10 = __builtin_amdgcn_mfma_f32_16x16x32_bf16(a1, b0, acc10, 0, 0, 0);
    acc11 = __builtin_amdgcn_mfma_f32_16x16x32_bf16(a1, b1, acc11, 0, 0, 0);
  }
  int quad = lane >> 4, nl = lane & 15;
  float* Mb = M + b * 262144;
  int i0 = blockIdx.y * 64 + wm * 32 + quad * 4;
  int j0 = blockIdx.x * 64 + wn * 32 + nl;
  #pragma unroll
  for (int r = 0; r < 4; ++r) {
    Mb[(i0 + r) * 512 + j0]           = acc00[r];
    Mb[(i0 + r) * 512 + j0 + 16]      = acc01[r];
    Mb[(i0 + 16 + r) * 512 + j0]      = acc10[r];
    Mb[(i0 + 16 + r) * 512 + j0 + 16] = acc11[r];
  }
}

// -------- bottleneck split-K (fp32, HBM-bound on 537MB W stream) --------
__global__ __launch_bounds__(256) void bot_partial_kernel(
    const float* __restrict__ m, const float* __restrict__ W, float* __restrict__ P) {
  __shared__ float Ws[32][128];
  __shared__ float Ms[32][16];
  int ic = blockIdx.x;
  int n0 = blockIdx.y * 128;
  int tid = threadIdx.x;
  int kb = ic * 1024;
  int wr = tid >> 1;
  int wc = (tid & 1) * 16;
  int nl = (tid & 63) * 2;
  int bq = (tid >> 6) * 4;
  float acc[4][2] = {};
  for (int k0 = kb; k0 < kb + 1024; k0 += 32) {
    #pragma unroll
    for (int q = 0; q < 4; ++q) {
      float4 wv = *(const float4*)(W + (n0 + wr) * KBOT + k0 + wc + q * 4);
      Ws[wc + q * 4 + 0][wr] = wv.x; Ws[wc + q * 4 + 1][wr] = wv.y;
      Ws[wc + q * 4 + 2][wr] = wv.z; Ws[wc + q * 4 + 3][wr] = wv.w;
    }
    if (tid < 128) {
      int b = tid >> 3, kg = (tid & 7) * 4;
      float4 mv = *(const float4*)(m + b * KBOT + k0 + kg);
      Ms[kg + 0][b] = mv.x; Ms[kg + 1][b] = mv.y; Ms[kg + 2][b] = mv.z; Ms[kg + 3][b] = mv.w;
    }
    __syncthreads();
    #pragma unroll
    for (int kk = 0; kk < 32; ++kk) {
      float2 w2 = *(const float2*)&Ws[kk][nl];
      float4 m4 = *(const float4*)&Ms[kk][bq];
      acc[0][0] = fmaf(m4.x, w2.x, acc[0][0]); acc[0][1] = fmaf(m4.x, w2.y, acc[0][1]);
      acc[1][0] = fmaf(m4.y, w2.x, acc[1][0]); acc[1][1] = fmaf(m4.y, w2.y, acc[1][1]);
      acc[2][0] = fmaf(m4.z, w2.x, acc[2][0]); acc[2][1] = fmaf(m4.z, w2.y, acc[2][1]);
      acc[3][0] = fmaf(m4.w, w2.x, acc[3][0]); acc[3][1] = fmaf(m4.w, w2.y, acc[3][1]);
    }
    __syncthreads();
  }
  #pragma unroll
  for (int i = 0; i < 4; ++i) {
    float* row = P + (ic * 16 + bq + i) * 512 + n0;
    *(float2*)&row[nl] = make_float2(acc[i][0], acc[i][1]);
  }
}

__global__ __launch_bounds__(256) void bot_reduce_kernel(
    const float* __restrict__ P, float* __restrict__ h) {
  int idx = blockIdx.x * 256 + threadIdx.x;
  float s[8] = {};
  for (int ic = 0; ic < 256; ic += 8) {
    #pragma unroll
    for (int q = 0; q < 8; ++q) s[q] += P[(ic + q) * 8192 + idx];
  }
  h[idx] = ((s[0] + s[1]) + (s[2] + s[3])) + ((s[4] + s[5]) + (s[6] + s[7]));
}

// -------- bn2d + relu20 + emb GEMV + L2-normalize*10 --------
__global__ __launch_bounds__(512) void final_kernel(
    const float* __restrict__ h, const float* __restrict__ gb, const float* __restrict__ bb,
    const float* __restrict__ embw, const float* __restrict__ embb, float* __restrict__ out) {
  __shared__ float hn[512];
  __shared__ float red[8];
  int b = blockIdx.x, e = threadIdx.x;
  float s = 0.f, s2 = 0.f;
  #pragma unroll
  for (int q = 0; q < BB; ++q) {
    float v = h[q * 512 + e];
    s += v; s2 = fmaf(v, v, s2);
  }
  float mean = s * (1.f / BB);
  float var = s2 * (1.f / BB) - mean * mean;
  float scale = gb[e] * rsqrtf(var + 1e-5f);
  float val = fmaf(h[b * 512 + e] - mean, scale, bb[e]);
  hn[e] = fminf(fmaxf(val, 0.f), 20.f);
  __syncthreads();
  float acc = 0.f;
  const float* wr = embw + e * 512;
  for (int c = 0; c < 512; c += 4) {
    float4 w4 = *(const float4*)(wr + c);
    float4 h4 = *(const float4*)&hn[c];
    acc = fmaf(w4.x, h4.x, acc); acc = fmaf(w4.y, h4.y, acc);
    acc = fmaf(w4.z, h4.z, acc); acc = fmaf(w4.w, h4.w, acc);
  }
  acc += embb[e];
  float sq = acc * acc;
  #pragma unroll
  for (int off = 32; off > 0; off >>= 1) sq += __shfl_down(sq, off);
  if ((e & 63) == 0) red[e >> 6] = sq;
  __syncthreads();
  float tot = 0.f;
  #pragma unroll
  for (int q = 0; q < 8; ++q) tot += red[q];
  float norm = sqrtf(tot + 1e-10f);
  out[b * 512 + e] = acc * (10.f / norm);
}

extern "C" void kernel_launch(void* const* d_in, const int* in_sizes, int n_in,
                              void* d_out, int out_size, void* d_ws, size_t ws_size,
                              hipStream_t stream) {
  const float* input_x = (const float*)d_in[0];
  const float* w1 = (const float*)d_in[1];
  const float* g1 = (const float*)d_in[3];  const float* b1 = (const float*)d_in[4];
  const float* w2 = (const float*)d_in[5];
  const float* g2 = (const float*)d_in[7];  const float* b2 = (const float*)d_in[8];
  const float* w3 = (const float*)d_in[9];
  const float* g3 = (const float*)d_in[11]; const float* b3 = (const float*)d_in[12];
  const float* w4 = (const float*)d_in[13];
  const float* g4 = (const float*)d_in[15]; const float* b4 = (const float*)d_in[16];
  const float* w5 = (const float*)d_in[17];
  const float* g5 = (const float*)d_in[19]; const float* b5 = (const float*)d_in[20];
  const float* botw = (const float*)d_in[21];
  const float* gb = (const float*)d_in[23]; const float* bb = (const float*)d_in[24];
  const float* embw = (const float*)d_in[25]; const float* embb = (const float*)d_in[26];

  float* ws = (float*)d_ws;
  float* y1 = ws + OFF_Y1;
  float* y2 = ws + OFF_Y2;
  float* y3 = ws + OFF_Y3;
  float* y4 = ws + OFF_Y4;
  float* y5 = ws + OFF_Y5;
  float* M  = ws + OFF_M;
  float* P  = ws + OFF_P;
  float* Pp = ws + OFF_PP;
  float* h  = ws + OFF_H;
  float* SC = ws + OFF_SC;
  short* WPK = (short*)(ws + OFF_WPK);
  short* xb0 = (short*)(ws + OFF_XB0);
  short* xb1 = (short*)(ws + OFF_XB1);
  short* xb2 = (short*)(ws + OFF_XB2);
  short* xb3 = (short*)(ws + OFF_XB3);
  short* xb4 = (short*)(ws + OFF_XB4);
  short* x4f = (short*)(ws + OFF_X4F);
  short* x5f = (short*)(ws + OFF_X5F);
  float* out = (float*)d_out;

  pack_weights<<<dim3(3072, 5), 256, 0, stream>>>(w1, w2, w3, w4, w5, WPK);
  convert_in<<<1600, 256, 0, stream>>>(input_x, xb0);

  // conv1: K = 5 taps * 64 (padded-ch)
  gemm_mfma<5, 1, 400, 396, 64><<<dim3(99, 8), 256, 0, stream>>>(WPK + WP1, xb0, y1);
  bn_partial<<<64, 256, 0, stream>>>(y1, 6336, Pp);
  bn_final<<<1, 512, 0, stream>>>(Pp, g1, b1, 6336.f, SC + 0, SC + 512);
  bn_apply_bf<<<1584, 256, 0, stream>>>(y1, SC + 0, SC + 512, xb1);

  gemm_mfma<3, 2, 396, 392, 512><<<dim3(98, 8), 256, 0, stream>>>(WPK + WP2, xb1, y2);
  bn_partial<<<64, 256, 0, stream>>>(y2, 6272, Pp);
  bn_final<<<1, 512, 0, stream>>>(Pp, g2, b2, 6272.f, SC + 1024, SC + 1536);
  bn_apply_bf<<<1568, 256, 0, stream>>>(y2, SC + 1024, SC + 1536, xb2);

  gemm_mfma<3, 4, 392, 384, 512><<<dim3(96, 8), 256, 0, stream>>>(WPK + WP3, xb2, y3);
  bn_partial<<<64, 256, 0, stream>>>(y3, 6144, Pp);
  bn_final<<<1, 512, 0, stream>>>(Pp, g3, b3, 6144.f, SC + 2048, SC + 2560);
  bn_apply_bf<<<1536, 256, 0, stream>>>(y3, SC + 2048, SC + 2560, xb3);

  gemm_mfma<1, 0, 384, 384, 512><<<dim3(96, 8), 256, 0, stream>>>(WPK + WP4, xb3, y4);
  bn_partial<<<64, 256, 0, stream>>>(y4, 6144, Pp);
  bn_final<<<1, 512, 0, stream>>>(Pp, g4, b4, 6144.f, SC + 3072, SC + 3584);
  bn_apply_bf<<<1536, 256, 0, stream>>>(y4, SC + 3072, SC + 3584, xb4);

  gemm_mfma<1, 0, 384, 384, 512><<<dim3(96, 8), 256, 0, stream>>>(WPK + WP5, xb4, y5);
  bn_partial<<<64, 256, 0, stream>>>(y5, 6144, Pp);
  bn_final<<<1, 512, 0, stream>>>(Pp, g5, b5, 6144.f, SC + 4096, SC + 4608);

  apply_frag<<<dim3(6, 8, 16), 256, 0, stream>>>(y4, SC + 3072, SC + 3584, x4f);
  apply_frag<<<dim3(6, 8, 16), 256, 0, stream>>>(y5, SC + 4096, SC + 4608, x5f);

  outer_mfma<<<dim3(8, 8, 16), 256, 0, stream>>>(x4f, x5f, M);
  bot_partial_kernel<<<dim3(256, 4), 256, 0, stream>>>(M, botw, P);
  bot_reduce_kernel<<<32, 256, 0, stream>>>(P, h);
  final_kernel<<<16, 512, 0, stream>>>(h, gb, bb, embw, embb, out);
}